// Round 7
// baseline (1658.240 us; speedup 1.0000x reference)
//
#include <hip/hip_runtime.h>
#include <math.h>

#define C1F 1.0e-4f   // 0.01^2
#define C2F 9.0e-4f   // 0.03^2
#define TX 32
#define TY 8
#define NSTAGE ((TY + 2) * (TX + 2))   // 340

// acc layout: per scale i (0..3), base = i*8
//  +0: sum |left_est - lpy|      +1: sum |right_est - rpy|
//  +2: sum |rl_disp - dl|        +3: sum |lr_disp - dr|
//  +4: sum x-grad smooth (dl+dr) +5: sum y-grad smooth (dl+dr)
//  +6: sum ssim_l (clipped)      +7: sum ssim_r
// acc[64] (as unsigned): completion ticket for fused finale.

struct F3 { float x, y, z; };   // natural 4B alignment -> dwordx3 loads
__device__ __forceinline__ F3 ld3(const float* p) { return *(const F3*)p; }

struct ScaleArgs {
    const float* disp;   // scale-res disparity (planar, as input)
    const float* lp;     // left image: packed RGB (stride 3) or planar
    const float* rp;     // right image
    int h, w, nx, ny, blk0, accoff, ntiles;
};

__device__ __forceinline__ float2 f2(float v) { return make_float2(v, v); }
__device__ __forceinline__ float2 f2abs(float2 a) {
    return make_float2(fabsf(a.x), fabsf(a.y));
}

__device__ __forceinline__ void warp_coeffs(float px, int W, int& i0, int& i1,
                                            float& w0, float& w1) {
    float x0f = floorf(px);
    float f = px - x0f;
    int x0i = (int)x0f;
    int x1i = x0i + 1;
    float v0 = (x0i >= 0 && x0i < W) ? 1.f : 0.f;
    float v1 = (x1i >= 0 && x1i < W) ? 1.f : 0.f;
    i0 = min(max(x0i, 0), W - 1);
    i1 = min(max(x1i, 0), W - 1);
    w0 = v0 * (1.f - f);
    w1 = v1 * f;
}

template<int N>
__device__ __forceinline__ void block_acc(const float* vals, float* gacc) {
    __shared__ float sacc[N];
    if (threadIdx.x < N) sacc[threadIdx.x] = 0.f;
    __syncthreads();
#pragma unroll
    for (int k = 0; k < N; ++k) {
        float v = vals[k];
#pragma unroll
        for (int off = 32; off > 0; off >>= 1) v += __shfl_down(v, off, 64);
        if ((threadIdx.x & 63) == 0) atomicAdd(&sacc[k], v);
    }
    __syncthreads();
    if (threadIdx.x < N) atomicAdd(&gacc[threadIdx.x], sacc[threadIdx.x]);
}

// Bijective XCD-chunked swizzle (m204 form).
__device__ __forceinline__ int xcd_swz(int orig, int n) {
    int q = n >> 3, r = n & 7;
    int x = orig & 7;
    int base = (x < r) ? x * (q + 1) : r * (q + 1) + (x - r) * q;
    return base + (orig >> 3);
}

// ---- fused loss tile: R0 structure (19KB LDS, high occupancy, direct global
// gathers).  PACKED=true reads interleaved-RGB images: 8 loads/slot touching
// 1/3 the cache lines of planar's 20 -> less latency pressure. ----
template<bool PACKED>
__device__ void fused_tile(const ScaleArgs& sa, int t,
                           float* __restrict__ accbase,
                           float4* __restrict__ simg,     // [3*NSTAGE] le,re,lv,rv
                           float2* __restrict__ sdisp) {  // [NSTAGE]
    const int h = sa.h, w = sa.w;
    float* acc = accbase + sa.accoff;

    const int tileX = t % sa.nx;
    int t2 = t / sa.nx;
    const int tileY = t2 % sa.ny;
    const int b = t2 / sa.ny;

    const int xo0 = tileX * TX, yo0 = tileY * TY;
    const int tid = threadIdx.x;
    const float Wm1 = (float)(w - 1);
    const float invWm1 = 1.f / Wm1;
    const int chs = h * w;

    const float* __restrict__ dl_base = sa.disp + (b * 2 + 0) * chs;
    const float* __restrict__ dr_base = sa.disp + (b * 2 + 1) * chs;

    if (PACKED) {
        const float* __restrict__ Lb = sa.lp + (size_t)b * chs * 3;
        const float* __restrict__ Rb = sa.rp + (size_t)b * chs * 3;
        for (int i = tid; i < NSTAGE; i += 256) {
            int sx = i % (TX + 2);
            int sy = i / (TX + 2);
            int x = min(max(xo0 - 1 + sx, 0), w - 1);
            int y = min(max(yo0 - 1 + sy, 0), h - 1);
            int off = y * w + x;
            float dl = dl_base[off];
            float dr = dr_base[off];
            float xb = (float)x * invWm1;
            int i0L, i1L, i0R, i1R;
            float w0L, w1L, w0R, w1R;
            warp_coeffs((xb - dl) * Wm1, w, i0L, i1L, w0L, w1L);
            warp_coeffs((xb + dr) * Wm1, w, i0R, i1R, w0R, w1R);
            const float* rowL = Lb + (size_t)(y * w) * 3;
            const float* rowR = Rb + (size_t)(y * w) * 3;
            F3 lv = ld3(rowL + 3 * x);
            F3 gl0 = ld3(rowL + 3 * i0R);
            F3 gl1 = ld3(rowL + 3 * i1R);
            F3 rv = ld3(rowR + 3 * x);
            F3 gr0 = ld3(rowR + 3 * i0L);
            F3 gr1 = ld3(rowR + 3 * i1L);
            sdisp[i] = make_float2(dl, dr);
            simg[0 * NSTAGE + i] = make_float4(gr0.x * w0L + gr1.x * w1L,
                                               gl0.x * w0R + gl1.x * w1R, lv.x, rv.x);
            simg[1 * NSTAGE + i] = make_float4(gr0.y * w0L + gr1.y * w1L,
                                               gl0.y * w0R + gl1.y * w1R, lv.y, rv.y);
            simg[2 * NSTAGE + i] = make_float4(gr0.z * w0L + gr1.z * w1L,
                                               gl0.z * w0R + gl1.z * w1R, lv.z, rv.z);
        }
    } else {
        const float* __restrict__ limg = sa.lp + (size_t)b * 3 * chs;
        const float* __restrict__ rimg = sa.rp + (size_t)b * 3 * chs;
        for (int i = tid; i < NSTAGE; i += 256) {
            int sx = i % (TX + 2);
            int sy = i / (TX + 2);
            int x = min(max(xo0 - 1 + sx, 0), w - 1);
            int y = min(max(yo0 - 1 + sy, 0), h - 1);
            int off = y * w + x;
            float dl = dl_base[off];
            float dr = dr_base[off];
            float xb = (float)x * invWm1;
            int i0L, i1L, i0R, i1R;
            float w0L, w1L, w0R, w1R;
            warp_coeffs((xb - dl) * Wm1, w, i0L, i1L, w0L, w1L);
            warp_coeffs((xb + dr) * Wm1, w, i0R, i1R, w0R, w1R);
            int rowoff = y * w;
            sdisp[i] = make_float2(dl, dr);
#pragma unroll
            for (int c = 0; c < 3; ++c) {
                int co = c * chs + rowoff;
                float le = rimg[co + i0L] * w0L + rimg[co + i1L] * w1L;
                float re = limg[co + i0R] * w0R + limg[co + i1R] * w1R;
                simg[c * NSTAGE + i] = make_float4(le, re, limg[co + x], rimg[co + x]);
            }
        }
    }
    __syncthreads();

    // ---- compute phase: R0 verbatim ----
    float sums[8] = {0.f, 0.f, 0.f, 0.f, 0.f, 0.f, 0.f, 0.f};
    const int tx = tid % TX, ty = tid / TX;
    const int x = xo0 + tx, y = yo0 + ty;
    if (x < w && y < h) {
        const int s = (ty + 1) * (TX + 2) + (tx + 1);
        float2 dd = sdisp[s];
        float dl = dd.x, dr = dd.y;
#pragma unroll
        for (int c = 0; c < 3; ++c) {
            float4 v = simg[c * NSTAGE + s];
            float2 d = f2abs(make_float2(v.x, v.y) - make_float2(v.z, v.w));
            sums[0] += d.x;
            sums[1] += d.y;
        }
        // LR consistency (far gathers on disp rows -> global)
        {
            float xb = (float)x * invWm1;
            int i0, i1; float w0, w1;
            warp_coeffs((xb - dl) * Wm1, w, i0, i1, w0, w1);
            const float* dr_row = dr_base + y * w;
            float rl = dr_row[i0] * w0 + dr_row[i1] * w1;
            sums[2] += fabsf(rl - dl);
            warp_coeffs((xb + dr) * Wm1, w, i0, i1, w0, w1);
            const float* dl_row = dl_base + y * w;
            float lr = dl_row[i0] * w0 + dl_row[i1] * w1;
            sums[3] += fabsf(lr - dr);
        }
        const float third = 1.f / 3.f;
        if (x < w - 1) {
            float2 d1 = sdisp[s + 1];
            float2 alr = f2(0.f);
#pragma unroll
            for (int c = 0; c < 3; ++c) {
                float4 v = simg[c * NSTAGE + s];
                float4 v1 = simg[c * NSTAGE + s + 1];
                alr = alr + f2abs(make_float2(v.z, v.w) - make_float2(v1.z, v1.w));
            }
            sums[4] += fabsf((dl - d1.x) * __expf(-alr.x * third)) +
                       fabsf((dr - d1.y) * __expf(-alr.y * third));
        }
        if (y < h - 1) {
            float2 d1 = sdisp[s + (TX + 2)];
            float2 alr = f2(0.f);
#pragma unroll
            for (int c = 0; c < 3; ++c) {
                float4 v = simg[c * NSTAGE + s];
                float4 v1 = simg[c * NSTAGE + s + (TX + 2)];
                alr = alr + f2abs(make_float2(v.z, v.w) - make_float2(v1.z, v1.w));
            }
            sums[5] += fabsf((dl - d1.x) * __expf(-alr.x * third)) +
                       fabsf((dr - d1.y) * __expf(-alr.y * third));
        }
        if (x >= 1 && x <= w - 2 && y >= 1 && y <= h - 2) {
            const float2 inv9 = f2(1.f / 9.f);
            const float2 c1 = f2(C1F), c2 = f2(C2F);
            const float2 two = f2(2.f), one = f2(1.f), half_ = f2(0.5f);
#pragma unroll 1
            for (int c = 0; c < 3; ++c) {
                float2 sX = f2(0.f), sY = f2(0.f);
                float2 sXX = f2(0.f), sYY = f2(0.f), sXY = f2(0.f);
#pragma unroll
                for (int dy = 0; dy < 3; ++dy) {
#pragma unroll
                    for (int dx = 0; dx < 3; ++dx) {
                        float4 v = simg[c * NSTAGE + (ty + dy) * (TX + 2) + (tx + dx)];
                        float2 a = make_float2(v.x, v.y);
                        float2 bb = make_float2(v.z, v.w);
                        sX = sX + a;
                        sY = sY + bb;
                        sXX = sXX + a * a;
                        sYY = sYY + bb * bb;
                        sXY = sXY + a * bb;
                    }
                }
                float2 mx = sX * inv9, my = sY * inv9;
                float2 vx = sXX * inv9 - mx * mx;
                float2 vy = sYY * inv9 - my * my;
                float2 vxy = sXY * inv9 - mx * my;
                float2 num = (two * mx * my + c1) * (two * vxy + c2);
                float2 den = (mx * mx + my * my + c1) * (vx + vy + c2);
                float2 ss = make_float2(num.x * __builtin_amdgcn_rcpf(den.x),
                                        num.y * __builtin_amdgcn_rcpf(den.y));
                float2 v = (one - ss) * half_;
                sums[6] += fminf(fmaxf(v.x, 0.f), 1.f);
                sums[7] += fminf(fmaxf(v.y, 0.f), 1.f);
            }
        }
    }
    block_acc<8>(sums, acc);
}

// ---- merged tile kernel: all 4 scales + ticket-fused finale ----
template<bool PACKED>
__global__ void __launch_bounds__(256, 4)
k_tiles(ScaleArgs s0, ScaleArgs s1, ScaleArgs s2, ScaleArgs s3,
        float* __restrict__ accbase, float* __restrict__ out, int nTotal) {
    __shared__ float4 simg[3 * NSTAGE];
    __shared__ float2 sdisp[NSTAGE];

    int blk = (int)blockIdx.x;
    ScaleArgs sa = (blk >= s3.blk0) ? s3
                 : (blk >= s2.blk0) ? s2
                 : (blk >= s1.blk0) ? s1 : s0;
    int t = xcd_swz(blk - sa.blk0, sa.ntiles);
    fused_tile<PACKED>(sa, t, accbase, simg, sdisp);

    __syncthreads();
    if (threadIdx.x == 0) {
        __threadfence();
        unsigned* tic = (unsigned*)(accbase + 64);
        unsigned prev = __hip_atomic_fetch_add(tic, 1u, __ATOMIC_ACQ_REL,
                                               __HIP_MEMORY_SCOPE_AGENT);
        if (prev == (unsigned)(nTotal - 1)) {
            float a[32];
#pragma unroll 1
            for (int k = 0; k < 32; ++k)
                a[k] = __hip_atomic_load(&accbase[k], __ATOMIC_RELAXED,
                                         __HIP_MEMORY_SCOPE_AGENT);
            float img = 0.f, lr = 0.f, sm = 0.f;
#pragma unroll 1
            for (int i = 0; i < 4; ++i) {
                int r = 1 << i;
                int h = 384 >> i, w = 768 >> i;
                const float* ac = a + i * 8;
                float Nl1 = 16.f * 3.f * (float)h * (float)w;
                float Nss = 16.f * 3.f * (float)(h - 2) * (float)(w - 2);
                float Nlr = 16.f * (float)h * (float)w;
                float Nsx = 16.f * (float)h * (float)(w - 1);
                float Nsy = 16.f * (float)(h - 1) * (float)w;
                img += 0.5f * (ac[6] / Nss) + 0.5f * (ac[0] / Nl1)
                     + 0.5f * (ac[7] / Nss) + 0.5f * (ac[1] / Nl1);
                lr += ac[2] / Nlr + ac[3] / Nlr;
                sm += (ac[4] / Nsx + ac[5] / Nsy) / (float)r;
            }
            out[0] = img + 0.1f * sm + 1.0f * lr;
        }
    }
}

// ================= prelude kernels =================
#define HW 294912            // 384*768
#define HALF_PX 4718592      // 16*HW
#define RPK_BLOCKS 36864     // 2*HALF_PX/256
#define N1P 2359296          // 2*16*192*384 positions
#define N2P 589824
#define N3P 147456
#define RESB 12096           // (N1P+N2P+N3P)/256
#define N1E 7077888LL        // planar elems: 2*16*3*192*384
#define N2E 1769472LL
#define N3E 442368LL
#define PL_BLOCKS 36288      // (N1E+N2E+N3E)/256

// packed-output resize: one thread per (img,b,y,x), writes float3
template<int OH, int OW>
__device__ __forceinline__ void resize_pos(int idx,
                                           const float* __restrict__ left,
                                           const float* __restrict__ right,
                                           float* __restrict__ lo,
                                           float* __restrict__ ro) {
    const int half = 16 * OH * OW;
    const float* src = left;
    float* dst = lo;
    if (idx >= half) { src = right; dst = ro; idx -= half; }
    int x = idx % OW;
    int t = idx / OW;
    int y = t % OH;
    int b = t / OH;
    float sy = (float)(384 - 1) / (float)(OH - 1);
    float sx = (float)(768 - 1) / (float)(OW - 1);
    float fy = y * sy;
    float fx = x * sx;
    int y0 = (int)floorf(fy); float wy = fy - (float)y0;
    int x0 = (int)floorf(fx); float wx = fx - (float)x0;
    int y1 = min(y0 + 1, 383); y0 = min(y0, 383);
    int x1 = min(x0 + 1, 767); x0 = min(x0, 767);
    F3 o;
    float* po = &o.x;
#pragma unroll
    for (int c = 0; c < 3; ++c) {
        const float* p = src + (size_t)(b * 3 + c) * HW;
        float a00 = p[y0 * 768 + x0];
        float a10 = p[y1 * 768 + x0];
        float a01 = p[y0 * 768 + x1];
        float a11 = p[y1 * 768 + x1];
        float r0 = a00 * (1.f - wy) + a10 * wy;
        float r1 = a01 * (1.f - wy) + a11 * wy;
        po[c] = r0 * (1.f - wx) + r1 * wx;
    }
    *(F3*)(dst + (size_t)idx * 3) = o;
}

// planar-output resize: one thread per element (R0 form)
template<int OH, int OW>
__device__ __forceinline__ void resize_elem(long long idx,
                                            const float* __restrict__ left,
                                            const float* __restrict__ right,
                                            float* __restrict__ lo,
                                            float* __restrict__ ro) {
    const long long half = (long long)16 * 3 * OH * OW;
    const float* src = left;
    float* dst = lo;
    if (idx >= half) { src = right; dst = ro; idx -= half; }
    int x = (int)(idx % OW);
    long long t = idx / OW;
    int y = (int)(t % OH);
    t /= OH;
    int c = (int)(t % 3);
    int b = (int)(t / 3);
    float sy = (float)(384 - 1) / (float)(OH - 1);
    float sx = (float)(768 - 1) / (float)(OW - 1);
    float fy = y * sy;
    float fx = x * sx;
    int y0 = (int)floorf(fy); float wy = fy - (float)y0;
    int x0 = (int)floorf(fx); float wx = fx - (float)x0;
    int y1 = min(y0 + 1, 383); y0 = min(y0, 383);
    int x1 = min(x0 + 1, 767); x0 = min(x0, 767);
    const float* p = src + (size_t)(b * 3 + c) * HW;
    float a00 = p[y0 * 768 + x0];
    float a10 = p[y1 * 768 + x0];
    float a01 = p[y0 * 768 + x1];
    float a11 = p[y1 * 768 + x1];
    float r0 = a00 * (1.f - wy) + a10 * wy;
    float r1 = a01 * (1.f - wy) + a11 * wy;
    dst[(((size_t)b * 3 + c) * OH + y) * OW + x] = r0 * (1.f - wx) + r1 * wx;
}

__global__ void __launch_bounds__(256)
k_prelude_pk(const float* __restrict__ left, const float* __restrict__ right,
             float* __restrict__ acc,
             float* __restrict__ pkL, float* __restrict__ pkR,
             float* __restrict__ p1L, float* __restrict__ p1R,
             float* __restrict__ p2L, float* __restrict__ p2R,
             float* __restrict__ p3L, float* __restrict__ p3R) {
    int blk = (int)blockIdx.x, tid = threadIdx.x;
    if (blk == 0 && tid < 128) acc[tid] = 0.f;
    if (blk < RPK_BLOCKS) {
        int idx = blk * 256 + tid;
        const float* src = left;
        float* dst = pkL;
        if (idx >= HALF_PX) { src = right; dst = pkR; idx -= HALF_PX; }
        int b = idx / HW;
        int rem = idx - b * HW;
        const float* p = src + (size_t)b * 3 * HW + rem;
        F3 v;
        v.x = p[0]; v.y = p[HW]; v.z = p[2 * HW];
        *(F3*)(dst + (size_t)idx * 3) = v;
        return;
    }
    int idx = (blk - RPK_BLOCKS) * 256 + tid;
    if (idx < N1P)              resize_pos<192, 384>(idx, left, right, p1L, p1R);
    else if (idx < N1P + N2P)   resize_pos<96, 192>(idx - N1P, left, right, p2L, p2R);
    else                        resize_pos<48, 96>(idx - N1P - N2P, left, right, p3L, p3R);
}

__global__ void __launch_bounds__(256)
k_prelude_pl(const float* __restrict__ left, const float* __restrict__ right,
             float* __restrict__ acc,
             float* __restrict__ lo1, float* __restrict__ ro1,
             float* __restrict__ lo2, float* __restrict__ ro2,
             float* __restrict__ lo3, float* __restrict__ ro3) {
    int blk = (int)blockIdx.x, tid = threadIdx.x;
    if (blk == 0 && tid < 128) acc[tid] = 0.f;
    long long idx = (long long)blk * 256 + tid;
    if (idx < N1E)                  resize_elem<192, 384>(idx, left, right, lo1, ro1);
    else if (idx < N1E + N2E)       resize_elem<96, 192>(idx - N1E, left, right, lo2, ro2);
    else                            resize_elem<48, 96>(idx - N1E - N2E, left, right, lo3, ro3);
}

extern "C" void kernel_launch(void* const* d_in, const int* in_sizes, int n_in,
                              void* d_out, int out_size, void* d_ws, size_t ws_size,
                              hipStream_t stream) {
    const int B = 16, H = 384, W = 768;
    const float* disp[4] = {(const float*)d_in[0], (const float*)d_in[1],
                            (const float*)d_in[2], (const float*)d_in[3]};
    const float* left = (const float*)d_in[4];
    const float* right = (const float*)d_in[5];
    float* out = (float*)d_out;
    float* acc = (float*)d_ws;

    // packed sizes (floats)
    const size_t szF = (size_t)B * H * W * 3;          // 14,155,776 per image
    const size_t sz1p = (size_t)B * 192 * 384 * 3;     // 3,538,944
    const size_t sz2p = (size_t)B * 96 * 192 * 3;
    const size_t sz3p = (size_t)B * 48 * 96 * 3;
    const size_t need_pk = (256 + 2 * (szF + sz1p + sz2p + sz3p)) * sizeof(float);
    const bool packed = ws_size >= need_pk;

    ScaleArgs sa[4];
    int blk0 = 0;
    for (int i = 0; i < 4; ++i) {
        int r = 1 << i;
        int h = H / r, w = W / r;
        sa[i].disp = disp[i];
        sa[i].h = h;
        sa[i].w = w;
        sa[i].nx = w / TX;
        sa[i].ny = h / TY;
        sa[i].accoff = i * 8;
        sa[i].ntiles = sa[i].nx * sa[i].ny * B;
        sa[i].blk0 = blk0;
        blk0 += sa[i].ntiles;
    }
    int nTotal = blk0;   // 18432 + 4608 + 1152 + 288 = 24480

    if (packed) {
        float* pkL = acc + 256;
        float* pkR = pkL + szF;
        float* p1L = pkR + szF;
        float* p1R = p1L + sz1p;
        float* p2L = p1R + sz1p;
        float* p2R = p2L + sz2p;
        float* p3L = p2R + sz2p;
        float* p3R = p3L + sz3p;
        const float* lp[4] = {pkL, p1L, p2L, p3L};
        const float* rp[4] = {pkR, p1R, p2R, p3R};
        for (int i = 0; i < 4; ++i) { sa[i].lp = lp[i]; sa[i].rp = rp[i]; }

        hipLaunchKernelGGL(k_prelude_pk, dim3(RPK_BLOCKS + RESB), dim3(256), 0, stream,
                           left, right, acc, pkL, pkR, p1L, p1R, p2L, p2R, p3L, p3R);
        hipLaunchKernelGGL(k_tiles<true>, dim3((unsigned)nTotal), dim3(256), 0, stream,
                           sa[0], sa[1], sa[2], sa[3], acc, out, nTotal);
    } else {
        float* pyr = acc + 256;
        size_t sz1 = (size_t)B * 3 * 192 * 384;
        size_t sz2 = (size_t)B * 3 * 96 * 192;
        size_t sz3 = (size_t)B * 3 * 48 * 96;
        float* lp1 = pyr;
        float* rp1 = lp1 + sz1;
        float* lp2 = rp1 + sz1;
        float* rp2 = lp2 + sz2;
        float* lp3 = rp2 + sz2;
        float* rp3 = lp3 + sz3;
        const float* lp[4] = {left, lp1, lp2, lp3};
        const float* rp[4] = {right, rp1, rp2, rp3};
        for (int i = 0; i < 4; ++i) { sa[i].lp = lp[i]; sa[i].rp = rp[i]; }

        hipLaunchKernelGGL(k_prelude_pl, dim3(PL_BLOCKS), dim3(256), 0, stream,
                           left, right, acc, lp1, rp1, lp2, rp2, lp3, rp3);
        hipLaunchKernelGGL(k_tiles<false>, dim3((unsigned)nTotal), dim3(256), 0, stream,
                           sa[0], sa[1], sa[2], sa[3], acc, out, nTotal);
    }
}

// Round 8
// 520.490 us; speedup vs baseline: 3.1859x; 3.1859x over previous
//
#include <hip/hip_runtime.h>
#include <math.h>

#define C1F 1.0e-4f   // 0.01^2
#define C2F 9.0e-4f   // 0.03^2
#define TX 32
#define TY 8
#define NSTAGE ((TY + 2) * (TX + 2))   // 340

// acc layout: per scale i (0..3), base = i*8
//  +0: sum |left_est - lpy|      +1: sum |right_est - rpy|
//  +2: sum |rl_disp - dl|        +3: sum |lr_disp - dr|
//  +4: sum x-grad smooth (dl+dr) +5: sum y-grad smooth (dl+dr)
//  +6: sum ssim_l (clipped)      +7: sum ssim_r
// NOTE: no ticket/threadfence — per-block agent-scope fences forced L2
// writeback+invalidate on non-coherent-XCD hardware (R7: 1535us @ 7% VALU).
// Final reduction is a separate 1-block kernel (R0-proven).

struct F3 { float x, y, z; };   // natural 4B alignment -> dwordx3 loads
__device__ __forceinline__ F3 ld3(const float* p) { return *(const F3*)p; }

struct ScaleArgs {
    const float* disp;   // scale-res disparity (planar, as input)
    const float* lp;     // left image: packed RGB (stride 3) or planar
    const float* rp;     // right image
    int h, w, nx, ny, blk0, accoff, ntiles;
};

__device__ __forceinline__ float2 f2(float v) { return make_float2(v, v); }
__device__ __forceinline__ float2 f2abs(float2 a) {
    return make_float2(fabsf(a.x), fabsf(a.y));
}

__device__ __forceinline__ void warp_coeffs(float px, int W, int& i0, int& i1,
                                            float& w0, float& w1) {
    float x0f = floorf(px);
    float f = px - x0f;
    int x0i = (int)x0f;
    int x1i = x0i + 1;
    float v0 = (x0i >= 0 && x0i < W) ? 1.f : 0.f;
    float v1 = (x1i >= 0 && x1i < W) ? 1.f : 0.f;
    i0 = min(max(x0i, 0), W - 1);
    i1 = min(max(x1i, 0), W - 1);
    w0 = v0 * (1.f - f);
    w1 = v1 * f;
}

template<int N>
__device__ __forceinline__ void block_acc(const float* vals, float* gacc) {
    __shared__ float sacc[N];
    if (threadIdx.x < N) sacc[threadIdx.x] = 0.f;
    __syncthreads();
#pragma unroll
    for (int k = 0; k < N; ++k) {
        float v = vals[k];
#pragma unroll
        for (int off = 32; off > 0; off >>= 1) v += __shfl_down(v, off, 64);
        if ((threadIdx.x & 63) == 0) atomicAdd(&sacc[k], v);
    }
    __syncthreads();
    if (threadIdx.x < N) atomicAdd(&gacc[threadIdx.x], sacc[threadIdx.x]);
}

// Bijective XCD-chunked swizzle (m204 form).
__device__ __forceinline__ int xcd_swz(int orig, int n) {
    int q = n >> 3, r = n & 7;
    int x = orig & 7;
    int base = (x < r) ? x * (q + 1) : r * (q + 1) + (x - r) * q;
    return base + (orig >> 3);
}

// ---- fused loss tile: R0 structure (19KB LDS, high occupancy, direct global
// gathers).  PACKED=true reads interleaved-RGB images: 8 loads/slot touching
// 1/3 the cache lines of planar's 20 -> less latency pressure. ----
template<bool PACKED>
__device__ void fused_tile(const ScaleArgs& sa, int t,
                           float* __restrict__ accbase,
                           float4* __restrict__ simg,     // [3*NSTAGE] le,re,lv,rv
                           float2* __restrict__ sdisp) {  // [NSTAGE]
    const int h = sa.h, w = sa.w;
    float* acc = accbase + sa.accoff;

    const int tileX = t % sa.nx;
    int t2 = t / sa.nx;
    const int tileY = t2 % sa.ny;
    const int b = t2 / sa.ny;

    const int xo0 = tileX * TX, yo0 = tileY * TY;
    const int tid = threadIdx.x;
    const float Wm1 = (float)(w - 1);
    const float invWm1 = 1.f / Wm1;
    const int chs = h * w;

    const float* __restrict__ dl_base = sa.disp + (b * 2 + 0) * chs;
    const float* __restrict__ dr_base = sa.disp + (b * 2 + 1) * chs;

    if (PACKED) {
        const float* __restrict__ Lb = sa.lp + (size_t)b * chs * 3;
        const float* __restrict__ Rb = sa.rp + (size_t)b * chs * 3;
        for (int i = tid; i < NSTAGE; i += 256) {
            int sx = i % (TX + 2);
            int sy = i / (TX + 2);
            int x = min(max(xo0 - 1 + sx, 0), w - 1);
            int y = min(max(yo0 - 1 + sy, 0), h - 1);
            int off = y * w + x;
            float dl = dl_base[off];
            float dr = dr_base[off];
            float xb = (float)x * invWm1;
            int i0L, i1L, i0R, i1R;
            float w0L, w1L, w0R, w1R;
            warp_coeffs((xb - dl) * Wm1, w, i0L, i1L, w0L, w1L);
            warp_coeffs((xb + dr) * Wm1, w, i0R, i1R, w0R, w1R);
            const float* rowL = Lb + (size_t)(y * w) * 3;
            const float* rowR = Rb + (size_t)(y * w) * 3;
            F3 lv = ld3(rowL + 3 * x);
            F3 gl0 = ld3(rowL + 3 * i0R);
            F3 gl1 = ld3(rowL + 3 * i1R);
            F3 rv = ld3(rowR + 3 * x);
            F3 gr0 = ld3(rowR + 3 * i0L);
            F3 gr1 = ld3(rowR + 3 * i1L);
            sdisp[i] = make_float2(dl, dr);
            simg[0 * NSTAGE + i] = make_float4(gr0.x * w0L + gr1.x * w1L,
                                               gl0.x * w0R + gl1.x * w1R, lv.x, rv.x);
            simg[1 * NSTAGE + i] = make_float4(gr0.y * w0L + gr1.y * w1L,
                                               gl0.y * w0R + gl1.y * w1R, lv.y, rv.y);
            simg[2 * NSTAGE + i] = make_float4(gr0.z * w0L + gr1.z * w1L,
                                               gl0.z * w0R + gl1.z * w1R, lv.z, rv.z);
        }
    } else {
        const float* __restrict__ limg = sa.lp + (size_t)b * 3 * chs;
        const float* __restrict__ rimg = sa.rp + (size_t)b * 3 * chs;
        for (int i = tid; i < NSTAGE; i += 256) {
            int sx = i % (TX + 2);
            int sy = i / (TX + 2);
            int x = min(max(xo0 - 1 + sx, 0), w - 1);
            int y = min(max(yo0 - 1 + sy, 0), h - 1);
            int off = y * w + x;
            float dl = dl_base[off];
            float dr = dr_base[off];
            float xb = (float)x * invWm1;
            int i0L, i1L, i0R, i1R;
            float w0L, w1L, w0R, w1R;
            warp_coeffs((xb - dl) * Wm1, w, i0L, i1L, w0L, w1L);
            warp_coeffs((xb + dr) * Wm1, w, i0R, i1R, w0R, w1R);
            int rowoff = y * w;
            sdisp[i] = make_float2(dl, dr);
#pragma unroll
            for (int c = 0; c < 3; ++c) {
                int co = c * chs + rowoff;
                float le = rimg[co + i0L] * w0L + rimg[co + i1L] * w1L;
                float re = limg[co + i0R] * w0R + limg[co + i1R] * w1R;
                simg[c * NSTAGE + i] = make_float4(le, re, limg[co + x], rimg[co + x]);
            }
        }
    }
    __syncthreads();

    // ---- compute phase: R0 verbatim ----
    float sums[8] = {0.f, 0.f, 0.f, 0.f, 0.f, 0.f, 0.f, 0.f};
    const int tx = tid % TX, ty = tid / TX;
    const int x = xo0 + tx, y = yo0 + ty;
    if (x < w && y < h) {
        const int s = (ty + 1) * (TX + 2) + (tx + 1);
        float2 dd = sdisp[s];
        float dl = dd.x, dr = dd.y;
#pragma unroll
        for (int c = 0; c < 3; ++c) {
            float4 v = simg[c * NSTAGE + s];
            float2 d = f2abs(make_float2(v.x, v.y) - make_float2(v.z, v.w));
            sums[0] += d.x;
            sums[1] += d.y;
        }
        // LR consistency (far gathers on disp rows -> global)
        {
            float xb = (float)x * invWm1;
            int i0, i1; float w0, w1;
            warp_coeffs((xb - dl) * Wm1, w, i0, i1, w0, w1);
            const float* dr_row = dr_base + y * w;
            float rl = dr_row[i0] * w0 + dr_row[i1] * w1;
            sums[2] += fabsf(rl - dl);
            warp_coeffs((xb + dr) * Wm1, w, i0, i1, w0, w1);
            const float* dl_row = dl_base + y * w;
            float lr = dl_row[i0] * w0 + dl_row[i1] * w1;
            sums[3] += fabsf(lr - dr);
        }
        const float third = 1.f / 3.f;
        if (x < w - 1) {
            float2 d1 = sdisp[s + 1];
            float2 alr = f2(0.f);
#pragma unroll
            for (int c = 0; c < 3; ++c) {
                float4 v = simg[c * NSTAGE + s];
                float4 v1 = simg[c * NSTAGE + s + 1];
                alr = alr + f2abs(make_float2(v.z, v.w) - make_float2(v1.z, v1.w));
            }
            sums[4] += fabsf((dl - d1.x) * __expf(-alr.x * third)) +
                       fabsf((dr - d1.y) * __expf(-alr.y * third));
        }
        if (y < h - 1) {
            float2 d1 = sdisp[s + (TX + 2)];
            float2 alr = f2(0.f);
#pragma unroll
            for (int c = 0; c < 3; ++c) {
                float4 v = simg[c * NSTAGE + s];
                float4 v1 = simg[c * NSTAGE + s + (TX + 2)];
                alr = alr + f2abs(make_float2(v.z, v.w) - make_float2(v1.z, v1.w));
            }
            sums[5] += fabsf((dl - d1.x) * __expf(-alr.x * third)) +
                       fabsf((dr - d1.y) * __expf(-alr.y * third));
        }
        if (x >= 1 && x <= w - 2 && y >= 1 && y <= h - 2) {
            const float2 inv9 = f2(1.f / 9.f);
            const float2 c1 = f2(C1F), c2 = f2(C2F);
            const float2 two = f2(2.f), one = f2(1.f), half_ = f2(0.5f);
#pragma unroll 1
            for (int c = 0; c < 3; ++c) {
                float2 sX = f2(0.f), sY = f2(0.f);
                float2 sXX = f2(0.f), sYY = f2(0.f), sXY = f2(0.f);
#pragma unroll
                for (int dy = 0; dy < 3; ++dy) {
#pragma unroll
                    for (int dx = 0; dx < 3; ++dx) {
                        float4 v = simg[c * NSTAGE + (ty + dy) * (TX + 2) + (tx + dx)];
                        float2 a = make_float2(v.x, v.y);
                        float2 bb = make_float2(v.z, v.w);
                        sX = sX + a;
                        sY = sY + bb;
                        sXX = sXX + a * a;
                        sYY = sYY + bb * bb;
                        sXY = sXY + a * bb;
                    }
                }
                float2 mx = sX * inv9, my = sY * inv9;
                float2 vx = sXX * inv9 - mx * mx;
                float2 vy = sYY * inv9 - my * my;
                float2 vxy = sXY * inv9 - mx * my;
                float2 num = (two * mx * my + c1) * (two * vxy + c2);
                float2 den = (mx * mx + my * my + c1) * (vx + vy + c2);
                float2 ss = make_float2(num.x * __builtin_amdgcn_rcpf(den.x),
                                        num.y * __builtin_amdgcn_rcpf(den.y));
                float2 v = (one - ss) * half_;
                sums[6] += fminf(fmaxf(v.x, 0.f), 1.f);
                sums[7] += fminf(fmaxf(v.y, 0.f), 1.f);
            }
        }
    }
    block_acc<8>(sums, acc);
}

// ---- merged tile kernel: all 4 scales (no ticket, no fences) ----
template<bool PACKED>
__global__ void __launch_bounds__(256, 4)
k_tiles(ScaleArgs s0, ScaleArgs s1, ScaleArgs s2, ScaleArgs s3,
        float* __restrict__ accbase) {
    __shared__ float4 simg[3 * NSTAGE];
    __shared__ float2 sdisp[NSTAGE];

    int blk = (int)blockIdx.x;
    ScaleArgs sa = (blk >= s3.blk0) ? s3
                 : (blk >= s2.blk0) ? s2
                 : (blk >= s1.blk0) ? s1 : s0;
    int t = xcd_swz(blk - sa.blk0, sa.ntiles);
    fused_tile<PACKED>(sa, t, accbase, simg, sdisp);
}

__global__ void k_final(const float* __restrict__ acc, float* __restrict__ out) {
    if (threadIdx.x != 0 || blockIdx.x != 0) return;
    float img = 0.f, lr = 0.f, sm = 0.f;
    for (int i = 0; i < 4; ++i) {
        int r = 1 << i;
        int h = 384 >> i, w = 768 >> i;
        const float* a = acc + i * 8;
        float Nl1 = 16.f * 3.f * (float)h * (float)w;
        float Nss = 16.f * 3.f * (float)(h - 2) * (float)(w - 2);
        float Nlr = 16.f * (float)h * (float)w;
        float Nsx = 16.f * (float)h * (float)(w - 1);
        float Nsy = 16.f * (float)(h - 1) * (float)w;
        img += 0.5f * (a[6] / Nss) + 0.5f * (a[0] / Nl1)
             + 0.5f * (a[7] / Nss) + 0.5f * (a[1] / Nl1);
        lr += a[2] / Nlr + a[3] / Nlr;
        sm += (a[4] / Nsx + a[5] / Nsy) / (float)r;
    }
    out[0] = img + 0.1f * sm + 1.0f * lr;
}

// ================= prelude kernels =================
#define HW 294912            // 384*768
#define HALF_PX 4718592      // 16*HW
#define RPK_BLOCKS 36864     // 2*HALF_PX/256
#define N1P 2359296          // 2*16*192*384 positions
#define N2P 589824
#define N3P 147456
#define RESB 12096           // (N1P+N2P+N3P)/256
#define N1E 7077888LL        // planar elems: 2*16*3*192*384
#define N2E 1769472LL
#define N3E 442368LL
#define PL_BLOCKS 36288      // (N1E+N2E+N3E)/256

// packed-output resize: one thread per (img,b,y,x), writes float3
template<int OH, int OW>
__device__ __forceinline__ void resize_pos(int idx,
                                           const float* __restrict__ left,
                                           const float* __restrict__ right,
                                           float* __restrict__ lo,
                                           float* __restrict__ ro) {
    const int half = 16 * OH * OW;
    const float* src = left;
    float* dst = lo;
    if (idx >= half) { src = right; dst = ro; idx -= half; }
    int x = idx % OW;
    int t = idx / OW;
    int y = t % OH;
    int b = t / OH;
    float sy = (float)(384 - 1) / (float)(OH - 1);
    float sx = (float)(768 - 1) / (float)(OW - 1);
    float fy = y * sy;
    float fx = x * sx;
    int y0 = (int)floorf(fy); float wy = fy - (float)y0;
    int x0 = (int)floorf(fx); float wx = fx - (float)x0;
    int y1 = min(y0 + 1, 383); y0 = min(y0, 383);
    int x1 = min(x0 + 1, 767); x0 = min(x0, 767);
    F3 o;
    float* po = &o.x;
#pragma unroll
    for (int c = 0; c < 3; ++c) {
        const float* p = src + (size_t)(b * 3 + c) * HW;
        float a00 = p[y0 * 768 + x0];
        float a10 = p[y1 * 768 + x0];
        float a01 = p[y0 * 768 + x1];
        float a11 = p[y1 * 768 + x1];
        float r0 = a00 * (1.f - wy) + a10 * wy;
        float r1 = a01 * (1.f - wy) + a11 * wy;
        po[c] = r0 * (1.f - wx) + r1 * wx;
    }
    *(F3*)(dst + (size_t)idx * 3) = o;
}

// planar-output resize: one thread per element (R0 form)
template<int OH, int OW>
__device__ __forceinline__ void resize_elem(long long idx,
                                            const float* __restrict__ left,
                                            const float* __restrict__ right,
                                            float* __restrict__ lo,
                                            float* __restrict__ ro) {
    const long long half = (long long)16 * 3 * OH * OW;
    const float* src = left;
    float* dst = lo;
    if (idx >= half) { src = right; dst = ro; idx -= half; }
    int x = (int)(idx % OW);
    long long t = idx / OW;
    int y = (int)(t % OH);
    t /= OH;
    int c = (int)(t % 3);
    int b = (int)(t / 3);
    float sy = (float)(384 - 1) / (float)(OH - 1);
    float sx = (float)(768 - 1) / (float)(OW - 1);
    float fy = y * sy;
    float fx = x * sx;
    int y0 = (int)floorf(fy); float wy = fy - (float)y0;
    int x0 = (int)floorf(fx); float wx = fx - (float)x0;
    int y1 = min(y0 + 1, 383); y0 = min(y0, 383);
    int x1 = min(x0 + 1, 767); x0 = min(x0, 767);
    const float* p = src + (size_t)(b * 3 + c) * HW;
    float a00 = p[y0 * 768 + x0];
    float a10 = p[y1 * 768 + x0];
    float a01 = p[y0 * 768 + x1];
    float a11 = p[y1 * 768 + x1];
    float r0 = a00 * (1.f - wy) + a10 * wy;
    float r1 = a01 * (1.f - wy) + a11 * wy;
    dst[(((size_t)b * 3 + c) * OH + y) * OW + x] = r0 * (1.f - wx) + r1 * wx;
}

__global__ void __launch_bounds__(256)
k_prelude_pk(const float* __restrict__ left, const float* __restrict__ right,
             float* __restrict__ acc,
             float* __restrict__ pkL, float* __restrict__ pkR,
             float* __restrict__ p1L, float* __restrict__ p1R,
             float* __restrict__ p2L, float* __restrict__ p2R,
             float* __restrict__ p3L, float* __restrict__ p3R) {
    int blk = (int)blockIdx.x, tid = threadIdx.x;
    if (blk == 0 && tid < 128) acc[tid] = 0.f;
    if (blk < RPK_BLOCKS) {
        int idx = blk * 256 + tid;
        const float* src = left;
        float* dst = pkL;
        if (idx >= HALF_PX) { src = right; dst = pkR; idx -= HALF_PX; }
        int b = idx / HW;
        int rem = idx - b * HW;
        const float* p = src + (size_t)b * 3 * HW + rem;
        F3 v;
        v.x = p[0]; v.y = p[HW]; v.z = p[2 * HW];
        *(F3*)(dst + (size_t)idx * 3) = v;
        return;
    }
    int idx = (blk - RPK_BLOCKS) * 256 + tid;
    if (idx < N1P)              resize_pos<192, 384>(idx, left, right, p1L, p1R);
    else if (idx < N1P + N2P)   resize_pos<96, 192>(idx - N1P, left, right, p2L, p2R);
    else                        resize_pos<48, 96>(idx - N1P - N2P, left, right, p3L, p3R);
}

__global__ void __launch_bounds__(256)
k_prelude_pl(const float* __restrict__ left, const float* __restrict__ right,
             float* __restrict__ acc,
             float* __restrict__ lo1, float* __restrict__ ro1,
             float* __restrict__ lo2, float* __restrict__ ro2,
             float* __restrict__ lo3, float* __restrict__ ro3) {
    int blk = (int)blockIdx.x, tid = threadIdx.x;
    if (blk == 0 && tid < 128) acc[tid] = 0.f;
    long long idx = (long long)blk * 256 + tid;
    if (idx < N1E)                  resize_elem<192, 384>(idx, left, right, lo1, ro1);
    else if (idx < N1E + N2E)       resize_elem<96, 192>(idx - N1E, left, right, lo2, ro2);
    else                            resize_elem<48, 96>(idx - N1E - N2E, left, right, lo3, ro3);
}

extern "C" void kernel_launch(void* const* d_in, const int* in_sizes, int n_in,
                              void* d_out, int out_size, void* d_ws, size_t ws_size,
                              hipStream_t stream) {
    const int B = 16, H = 384, W = 768;
    const float* disp[4] = {(const float*)d_in[0], (const float*)d_in[1],
                            (const float*)d_in[2], (const float*)d_in[3]};
    const float* left = (const float*)d_in[4];
    const float* right = (const float*)d_in[5];
    float* out = (float*)d_out;
    float* acc = (float*)d_ws;

    // packed sizes (floats)
    const size_t szF = (size_t)B * H * W * 3;          // 14,155,776 per image
    const size_t sz1p = (size_t)B * 192 * 384 * 3;     // 3,538,944
    const size_t sz2p = (size_t)B * 96 * 192 * 3;
    const size_t sz3p = (size_t)B * 48 * 96 * 3;
    const size_t need_pk = (256 + 2 * (szF + sz1p + sz2p + sz3p)) * sizeof(float);
    const bool packed = ws_size >= need_pk;

    ScaleArgs sa[4];
    int blk0 = 0;
    for (int i = 0; i < 4; ++i) {
        int r = 1 << i;
        int h = H / r, w = W / r;
        sa[i].disp = disp[i];
        sa[i].h = h;
        sa[i].w = w;
        sa[i].nx = w / TX;
        sa[i].ny = h / TY;
        sa[i].accoff = i * 8;
        sa[i].ntiles = sa[i].nx * sa[i].ny * B;
        sa[i].blk0 = blk0;
        blk0 += sa[i].ntiles;
    }
    int nTotal = blk0;   // 18432 + 4608 + 1152 + 288 = 24480

    if (packed) {
        float* pkL = acc + 256;
        float* pkR = pkL + szF;
        float* p1L = pkR + szF;
        float* p1R = p1L + sz1p;
        float* p2L = p1R + sz1p;
        float* p2R = p2L + sz2p;
        float* p3L = p2R + sz2p;
        float* p3R = p3L + sz3p;
        const float* lp[4] = {pkL, p1L, p2L, p3L};
        const float* rp[4] = {pkR, p1R, p2R, p3R};
        for (int i = 0; i < 4; ++i) { sa[i].lp = lp[i]; sa[i].rp = rp[i]; }

        hipLaunchKernelGGL(k_prelude_pk, dim3(RPK_BLOCKS + RESB), dim3(256), 0, stream,
                           left, right, acc, pkL, pkR, p1L, p1R, p2L, p2R, p3L, p3R);
        hipLaunchKernelGGL(k_tiles<true>, dim3((unsigned)nTotal), dim3(256), 0, stream,
                           sa[0], sa[1], sa[2], sa[3], acc);
    } else {
        float* pyr = acc + 256;
        size_t sz1 = (size_t)B * 3 * 192 * 384;
        size_t sz2 = (size_t)B * 3 * 96 * 192;
        size_t sz3 = (size_t)B * 3 * 48 * 96;
        float* lp1 = pyr;
        float* rp1 = lp1 + sz1;
        float* lp2 = rp1 + sz1;
        float* rp2 = lp2 + sz2;
        float* lp3 = rp2 + sz2;
        float* rp3 = lp3 + sz3;
        const float* lp[4] = {left, lp1, lp2, lp3};
        const float* rp[4] = {right, rp1, rp2, rp3};
        for (int i = 0; i < 4; ++i) { sa[i].lp = lp[i]; sa[i].rp = rp[i]; }

        hipLaunchKernelGGL(k_prelude_pl, dim3(PL_BLOCKS), dim3(256), 0, stream,
                           left, right, acc, lp1, rp1, lp2, rp2, lp3, rp3);
        hipLaunchKernelGGL(k_tiles<false>, dim3((unsigned)nTotal), dim3(256), 0, stream,
                           sa[0], sa[1], sa[2], sa[3], acc);
    }
    hipLaunchKernelGGL(k_final, dim3(1), dim3(64), 0, stream, acc, out);
}